// Round 14
// baseline (337.124 us; speedup 1.0000x reference)
//
#include <hip/hip_runtime.h>
#include <math.h>

#define ROWS_TOTAL 8192
#define KDIM 1024
#define NPROTO 32
#define RNK 16
#define OUTD 1024
#define TIE_EPS 1.30e-4

// ---------------------------------------------------------------------------
// Kernel 1: routing (numerics identical to the PASSING round-7 kernel).
// ---------------------------------------------------------------------------
__global__ __launch_bounds__(256) void route_kernel(
    const float* __restrict__ x, const float* __restrict__ proto,
    const float* __restrict__ temp, float4* __restrict__ route,
    int* __restrict__ counts)
{
    __shared__ float Xs[16][68];
    __shared__ float Ps[64][33];
    __shared__ double x2s[16];
    __shared__ double p2s[32];
    __shared__ int lcnt[64];

    const int tid = threadIdx.x;
    const int rowbase = blockIdx.x * 16;
    const int frow = tid >> 4;
    const int fq   = tid & 15;
    const int c    = tid & 31;
    const int rg   = tid >> 5;

    if (tid < 64) lcnt[tid] = 0;

    double xsq = 0.0, p2a = 0.0, p2b = 0.0;
    double acc0 = 0.0, acc1 = 0.0;

    for (int kc = 0; kc < KDIM; kc += 64) {
        float4 xv = *(const float4*)(x + (rowbase + frow) * KDIM + kc + 4 * fq);
        xsq = fma((double)xv.x, (double)xv.x, xsq);
        xsq = fma((double)xv.y, (double)xv.y, xsq);
        xsq = fma((double)xv.z, (double)xv.z, xsq);
        xsq = fma((double)xv.w, (double)xv.w, xsq);
        *(float4*)(&Xs[frow][4 * fq]) = xv;
        float4 pa = *(const float4*)(proto + frow * KDIM + kc + 4 * fq);
        float4 pb = *(const float4*)(proto + (frow + 16) * KDIM + kc + 4 * fq);
        p2a = fma((double)pa.x, (double)pa.x, p2a);
        p2a = fma((double)pa.y, (double)pa.y, p2a);
        p2a = fma((double)pa.z, (double)pa.z, p2a);
        p2a = fma((double)pa.w, (double)pa.w, p2a);
        p2b = fma((double)pb.x, (double)pb.x, p2b);
        p2b = fma((double)pb.y, (double)pb.y, p2b);
        p2b = fma((double)pb.z, (double)pb.z, p2b);
        p2b = fma((double)pb.w, (double)pb.w, p2b);
        Ps[4 * fq + 0][frow] = pa.x;
        Ps[4 * fq + 1][frow] = pa.y;
        Ps[4 * fq + 2][frow] = pa.z;
        Ps[4 * fq + 3][frow] = pa.w;
        Ps[4 * fq + 0][frow + 16] = pb.x;
        Ps[4 * fq + 1][frow + 16] = pb.y;
        Ps[4 * fq + 2][frow + 16] = pb.z;
        Ps[4 * fq + 3][frow + 16] = pb.w;
        __syncthreads();
        #pragma unroll
        for (int k = 0; k < 64; k += 4) {
            float4 xa = *(const float4*)(&Xs[2 * rg][k]);
            float4 xb = *(const float4*)(&Xs[2 * rg + 1][k]);
            double q0 = (double)Ps[k][c],     q1 = (double)Ps[k + 1][c];
            double q2 = (double)Ps[k + 2][c], q3 = (double)Ps[k + 3][c];
            acc0 = fma((double)xa.x, q0, acc0);
            acc0 = fma((double)xa.y, q1, acc0);
            acc0 = fma((double)xa.z, q2, acc0);
            acc0 = fma((double)xa.w, q3, acc0);
            acc1 = fma((double)xb.x, q0, acc1);
            acc1 = fma((double)xb.y, q1, acc1);
            acc1 = fma((double)xb.z, q2, acc1);
            acc1 = fma((double)xb.w, q3, acc1);
        }
        __syncthreads();
    }

    #pragma unroll
    for (int m = 1; m < 16; m <<= 1) {
        xsq += __shfl_xor(xsq, m);
        p2a += __shfl_xor(p2a, m);
        p2b += __shfl_xor(p2b, m);
    }
    if (fq == 0) { x2s[frow] = xsq; p2s[frow] = p2a; p2s[frow + 16] = p2b; }
    __syncthreads();

    const double tmp = (double)fmaxf(fabsf(temp[0]), 0.1f);
    const double myp2 = p2s[c];

    #pragma unroll
    for (int which = 0; which < 2; ++which) {
        double key = myp2 - 2.0 * (which ? acc1 : acc0);
        double k1 = key, k2 = 1.0e300, k3 = 1.1e300;
        int    i1 = c,   i2 = 64,      i3 = 65;
        #pragma unroll
        for (int m = 1; m < 32; m <<= 1) {
            double b1 = __shfl_xor(k1, m), b2 = __shfl_xor(k2, m), b3 = __shfl_xor(k3, m);
            int    j1 = __shfl_xor(i1, m), j2 = __shfl_xor(i2, m), j3 = __shfl_xor(i3, m);
            bool c1 = k1 <= b1;
            double m1 = c1 ? k1 : b1, M1 = c1 ? b1 : k1;
            int   mi1 = c1 ? i1 : j1, Mi1 = c1 ? j1 : i1;
            bool c2 = k2 <= b2;
            double m2 = c2 ? k2 : b2;
            int   mi2 = c2 ? i2 : j2;
            bool c3 = k3 <= b3;
            double m3 = c3 ? k3 : b3;
            int   mi3 = c3 ? i3 : j3;
            bool c4 = M1 <= m2;
            double t2 = c4 ? M1 : m2,  T2 = c4 ? m2 : M1;
            int   ti2 = c4 ? Mi1 : mi2, Ti2 = c4 ? mi2 : Mi1;
            bool c5 = T2 <= m3;
            k1 = m1; i1 = mi1;
            k2 = t2; i2 = ti2;
            k3 = c5 ? T2 : m3; i3 = c5 ? Ti2 : mi3;
        }
        if (c == 0) {
            const int row = rowbase + 2 * rg + which;
            bool tie = (k3 - k2) < TIE_EPS;
            bool take3 = tie && (i3 < i2);
            double ksel = take3 ? k3 : k2;
            int    isel = take3 ? i3 : i2;
            double x2 = x2s[2 * rg + which];
            double d0 = sqrt(fmax(x2 + k1, 0.0));
            double d1 = sqrt(fmax(x2 + ksel, 0.0));
            float e  = expf((float)((d0 - d1) / tmp));
            float w0 = 1.f / (1.f + e);
            route[row] = make_float4(__int_as_float(i1), __int_as_float(isel),
                                     w0, e * w0);
            atomicAdd(&lcnt[i1], 1);
            atomicAdd(&lcnt[32 + isel], 1);
        }
    }
    __syncthreads();
    if (tid < 64) atomicAdd(&counts[tid], lcnt[tid]);
}

// counts[64] -> exclusive prefix per 32-slot segment; segs = (start,end).
__global__ __launch_bounds__(64) void scan_kernel(int* __restrict__ counts,
                                                  int2* __restrict__ segs)
{
    const int tid = threadIdx.x;
    int v = counts[tid];
    int sum = v;
    #pragma unroll
    for (int off = 1; off < 32; off <<= 1) {
        int u = __shfl_up(sum, off, 32);
        if ((tid & 31) >= off) sum += u;
    }
    int excl = sum - v;
    counts[tid] = excl;
    segs[tid] = make_int2(excl, excl + v);
}

__global__ __launch_bounds__(256) void scatter_kernel(
    const float4* __restrict__ route, int* __restrict__ counts,
    int* __restrict__ rowlist0, int* __restrict__ rowlist1)
{
    __shared__ int lcnt[64];
    __shared__ int gbase[64];
    const int tid = threadIdx.x;
    const int i = blockIdx.x * 256 + tid;
    if (tid < 64) lcnt[tid] = 0;
    __syncthreads();
    float4 rt = route[i];
    int p0 = __float_as_int(rt.x);
    int p1 = __float_as_int(rt.y);
    int lp0 = atomicAdd(&lcnt[p0], 1);
    int lp1 = atomicAdd(&lcnt[32 + p1], 1);
    __syncthreads();
    if (tid < 64) gbase[tid] = atomicAdd(&counts[tid], lcnt[tid]);
    __syncthreads();
    rowlist0[gbase[p0] + lp0] = i;
    rowlist1[gbase[32 + p1] + lp1] = i;
}

// ---------------------------------------------------------------------------
// Transpose kernel: Bt[p][k][r] = B[p][r][k], At[p][r][o] = A[p][o][r].
// ---------------------------------------------------------------------------
__global__ __launch_bounds__(256) void transpose_kernel(
    const float* __restrict__ A, const float* __restrict__ B,
    float* __restrict__ At, float* __restrict__ Bt)
{
    __shared__ float T[16 * 68];
    __shared__ float U[64 * 20];
    const int tid = threadIdx.x;
    const int p = blockIdx.x;
    const float4* B4 = (const float4*)(B + (size_t)p * RNK * KDIM);
    const float4* A4 = (const float4*)(A + (size_t)p * OUTD * RNK);
    float4* Bt4 = (float4*)(Bt + (size_t)p * KDIM * RNK);
    float4* At4 = (float4*)(At + (size_t)p * RNK * OUTD);

    for (int c = 0; c < 16; ++c) {
        {
            int r = tid >> 4, kk = tid & 15;
            float4 v = B4[r * 256 + c * 16 + kk];
            *(float4*)&T[r * 68 + kk * 4] = v;
        }
        {
            int o = tid >> 2, rq = tid & 3;
            float4 v = A4[(c * 64 + o) * 4 + rq];
            *(float4*)&U[o * 20 + rq * 4] = v;
        }
        __syncthreads();
        {
            int k = tid >> 2, rq = tid & 3;
            float4 g = make_float4(T[(rq * 4 + 0) * 68 + k], T[(rq * 4 + 1) * 68 + k],
                                   T[(rq * 4 + 2) * 68 + k], T[(rq * 4 + 3) * 68 + k]);
            Bt4[(c * 64 + k) * 4 + rq] = g;
        }
        {
            int r = tid >> 4, ow = tid & 15;
            float4 g = make_float4(U[(ow * 4 + 0) * 20 + r], U[(ow * 4 + 1) * 20 + r],
                                   U[(ow * 4 + 2) * 20 + r], U[(ow * 4 + 3) * 20 + r]);
            At4[r * 256 + c * 16 + ow] = g;
        }
        __syncthreads();
    }
}

// ---------------------------------------------------------------------------
// h-kernel: one 64-lane wave per 16 sorted same-proto entries (chunks are
// WITHIN segments -> proto wave-uniform). Thread (kq=l>>2, rq=l&3):
// 64 iters x {1 Bt float4 (1KB/wave contiguous) + 16 x scalars (L1
// broadcast) + 64 FMA} -> 4 FMA per weight byte. XOR-shfl reduce over kq,
// store h to hws[entry][16].
// ---------------------------------------------------------------------------
__global__ __launch_bounds__(64) void h_kernel(
    const float* __restrict__ x, const float* __restrict__ Bt,
    const int* __restrict__ rowlist0, const int* __restrict__ rowlist1,
    const int2* __restrict__ segs, float* __restrict__ hws)
{
    const int l = threadIdx.x;
    const int kq = l >> 2, rq = l & 3;
    const int s = blockIdx.y;             // 0..63 combined segment
    const int slot = s >> 5;
    const int2 sg = segs[s];
    const int* rl = slot ? rowlist1 : rowlist0;
    const float4* Btp = (const float4*)(Bt + (size_t)(s & 31) * KDIM * RNK);

    for (int c = blockIdx.x; ; c += gridDim.x) {
        const int base = sg.x + c * 16;
        if (base >= sg.y) break;
        const int m = min(16, sg.y - base);

        int xoff[16];
        #pragma unroll
        for (int e = 0; e < 16; ++e)
            xoff[e] = rl[base + min(e, m - 1)] * KDIM;

        float4 acc[16];
        #pragma unroll
        for (int e = 0; e < 16; ++e) acc[e] = make_float4(0.f, 0.f, 0.f, 0.f);

        #pragma unroll 4
        for (int i = 0; i < 64; ++i) {
            const int k = i * 16 + kq;
            float4 bv = Btp[k * 4 + rq];
            #pragma unroll
            for (int e = 0; e < 16; ++e) {
                float xv = x[xoff[e] + k];
                acc[e].x = fmaf(xv, bv.x, acc[e].x);
                acc[e].y = fmaf(xv, bv.y, acc[e].y);
                acc[e].z = fmaf(xv, bv.z, acc[e].z);
                acc[e].w = fmaf(xv, bv.w, acc[e].w);
            }
        }
        // reduce over kq (lane bits 2..5)
        #pragma unroll
        for (int msk = 4; msk < 64; msk <<= 1) {
            #pragma unroll
            for (int e = 0; e < 16; ++e) {
                acc[e].x += __shfl_xor(acc[e].x, msk);
                acc[e].y += __shfl_xor(acc[e].y, msk);
                acc[e].z += __shfl_xor(acc[e].z, msk);
                acc[e].w += __shfl_xor(acc[e].w, msk);
            }
        }
        if (kq == 0) {
            const int gbase = slot * ROWS_TOTAL + base;
            #pragma unroll
            for (int e = 0; e < 16; ++e) {
                int idx = gbase + min(e, m - 1);
                *(float4*)(hws + idx * 16 + rq * 4) = acc[e];
            }
        }
    }
}

// ---------------------------------------------------------------------------
// y-kernel: one wave per 16 sorted same-proto entries. h tile (16x16) in
// LDS; per At float4 load -> 64 FMA (16 entries). out writes 1KB-contiguous
// per entry. slot0 stores, slot1 RMW-adds (stream-ordered, race-free).
// ---------------------------------------------------------------------------
__global__ __launch_bounds__(64) void y_kernel(
    const float* __restrict__ At, const float* __restrict__ bias,
    const float4* __restrict__ route, const int* __restrict__ rowlist,
    const int2* __restrict__ segs, const float* __restrict__ hws,
    float* __restrict__ out, int slot)
{
    __shared__ float hsm[16][16];
    __shared__ int rows[16];
    __shared__ float wts[16];

    const int l = threadIdx.x;
    const int p = blockIdx.y;
    const int2 sg = segs[slot * 32 + p];
    const float4* Atp = (const float4*)(At + (size_t)p * RNK * OUTD);
    const float4* bp  = (const float4*)(bias + (size_t)p * OUTD);

    for (int c = blockIdx.x; ; c += gridDim.x) {
        const int base = sg.x + c * 16;
        if (base >= sg.y) break;
        const int m = min(16, sg.y - base);
        const int gbase = slot * ROWS_TOTAL + base;

        {
            const int e = l >> 2, rq4 = l & 3;
            int idx = gbase + min(e, m - 1);
            *(float4*)&hsm[e][rq4 * 4] = *(const float4*)(hws + idx * 16 + rq4 * 4);
        }
        if (l < 16) {
            int rr = rowlist[base + min(l, m - 1)];
            rows[l] = rr;
            float4 rt = route[rr];
            wts[l] = slot ? rt.w : rt.z;
        }
        __syncthreads();

        #pragma unroll
        for (int j = 0; j < 4; ++j) {
            const int f4 = j * 64 + l;
            float4 acc[16];
            #pragma unroll
            for (int e = 0; e < 16; ++e) acc[e] = make_float4(0.f, 0.f, 0.f, 0.f);

            #pragma unroll
            for (int rq4 = 0; rq4 < 4; ++rq4) {
                float4 a0 = Atp[(rq4 * 4 + 0) * 256 + f4];
                float4 a1 = Atp[(rq4 * 4 + 1) * 256 + f4];
                float4 a2 = Atp[(rq4 * 4 + 2) * 256 + f4];
                float4 a3 = Atp[(rq4 * 4 + 3) * 256 + f4];
                #pragma unroll
                for (int e = 0; e < 16; ++e) {
                    float4 hq = *(const float4*)&hsm[e][rq4 * 4];
                    acc[e].x = fmaf(hq.x, a0.x, acc[e].x);
                    acc[e].y = fmaf(hq.x, a0.y, acc[e].y);
                    acc[e].z = fmaf(hq.x, a0.z, acc[e].z);
                    acc[e].w = fmaf(hq.x, a0.w, acc[e].w);
                    acc[e].x = fmaf(hq.y, a1.x, acc[e].x);
                    acc[e].y = fmaf(hq.y, a1.y, acc[e].y);
                    acc[e].z = fmaf(hq.y, a1.z, acc[e].z);
                    acc[e].w = fmaf(hq.y, a1.w, acc[e].w);
                    acc[e].x = fmaf(hq.z, a2.x, acc[e].x);
                    acc[e].y = fmaf(hq.z, a2.y, acc[e].y);
                    acc[e].z = fmaf(hq.z, a2.z, acc[e].z);
                    acc[e].w = fmaf(hq.z, a2.w, acc[e].w);
                    acc[e].x = fmaf(hq.w, a3.x, acc[e].x);
                    acc[e].y = fmaf(hq.w, a3.y, acc[e].y);
                    acc[e].z = fmaf(hq.w, a3.z, acc[e].z);
                    acc[e].w = fmaf(hq.w, a3.w, acc[e].w);
                }
            }
            float4 bb = bp[f4];
            for (int e = 0; e < m; ++e) {
                const float w = wts[e];
                float4 v = make_float4(w * (acc[e].x + bb.x), w * (acc[e].y + bb.y),
                                       w * (acc[e].z + bb.z), w * (acc[e].w + bb.w));
                float4* dst = (float4*)(out + (size_t)rows[e] * OUTD + f4 * 4);
                if (slot) {
                    float4 old = *dst;
                    v.x += old.x; v.y += old.y; v.z += old.z; v.w += old.w;
                }
                *dst = v;
            }
        }
        __syncthreads();
    }
}

extern "C" void kernel_launch(void* const* d_in, const int* in_sizes, int n_in,
                              void* d_out, int out_size, void* d_ws, size_t ws_size,
                              hipStream_t stream) {
    const float* x     = (const float*)d_in[0];
    const float* proto = (const float*)d_in[1];
    const float* B     = (const float*)d_in[2];
    const float* A     = (const float*)d_in[3];
    const float* bias  = (const float*)d_in[4];
    const float* temp  = (const float*)d_in[5];
    float* out = (float*)d_out;

    char* wsb = (char*)d_ws;
    float4* route = (float4*)wsb;                              // 128 KB
    int* rowlist0 = (int*)(wsb + 131072);                      // 32 KB
    int* rowlist1 = rowlist0 + ROWS_TOTAL;                     // 32 KB
    int* counts   = rowlist1 + ROWS_TOTAL;                     // 256 B
    int2* segs    = (int2*)(counts + 64);                      // 512 B
    float* Bt     = (float*)(wsb + 262144);                    // 2 MB
    float* At     = (float*)(wsb + 262144 + 2097152);          // 2 MB
    float* hws    = (float*)(wsb + 262144 + 2 * 2097152);      // 1 MB

    hipMemsetAsync(counts, 0, 64 * sizeof(int), stream);
    transpose_kernel<<<NPROTO, 256, 0, stream>>>(A, B, At, Bt);
    route_kernel<<<ROWS_TOTAL / 16, 256, 0, stream>>>(x, proto, temp, route, counts);
    scan_kernel<<<1, 64, 0, stream>>>(counts, segs);
    scatter_kernel<<<ROWS_TOTAL / 256, 256, 0, stream>>>(route, counts, rowlist0, rowlist1);
    h_kernel<<<dim3(32, 64), 64, 0, stream>>>(x, Bt, rowlist0, rowlist1, segs, hws);
    y_kernel<<<dim3(32, NPROTO), 64, 0, stream>>>(At, bias, route, rowlist0, segs, hws, out, 0);
    y_kernel<<<dim3(32, NPROTO), 64, 0, stream>>>(At, bias, route, rowlist1, segs, hws, out, 1);
}

// Round 15
// 175.351 us; speedup vs baseline: 1.9226x; 1.9226x over previous
//
#include <hip/hip_runtime.h>
#include <math.h>

#define ROWS_TOTAL 8192
#define KDIM 1024
#define NPROTO 32
#define RNK 16
#define OUTD 1024
#define TIE_EPS 1.30e-4

// ---------------------------------------------------------------------------
// Kernel 1: routing (numerics identical to the PASSING round-7 kernel).
// ---------------------------------------------------------------------------
__global__ __launch_bounds__(256) void route_kernel(
    const float* __restrict__ x, const float* __restrict__ proto,
    const float* __restrict__ temp, float4* __restrict__ route,
    int* __restrict__ counts)
{
    __shared__ float Xs[16][68];
    __shared__ float Ps[64][33];
    __shared__ double x2s[16];
    __shared__ double p2s[32];
    __shared__ int lcnt[64];

    const int tid = threadIdx.x;
    const int rowbase = blockIdx.x * 16;
    const int frow = tid >> 4;
    const int fq   = tid & 15;
    const int c    = tid & 31;
    const int rg   = tid >> 5;

    if (tid < 64) lcnt[tid] = 0;

    double xsq = 0.0, p2a = 0.0, p2b = 0.0;
    double acc0 = 0.0, acc1 = 0.0;

    for (int kc = 0; kc < KDIM; kc += 64) {
        float4 xv = *(const float4*)(x + (rowbase + frow) * KDIM + kc + 4 * fq);
        xsq = fma((double)xv.x, (double)xv.x, xsq);
        xsq = fma((double)xv.y, (double)xv.y, xsq);
        xsq = fma((double)xv.z, (double)xv.z, xsq);
        xsq = fma((double)xv.w, (double)xv.w, xsq);
        *(float4*)(&Xs[frow][4 * fq]) = xv;
        float4 pa = *(const float4*)(proto + frow * KDIM + kc + 4 * fq);
        float4 pb = *(const float4*)(proto + (frow + 16) * KDIM + kc + 4 * fq);
        p2a = fma((double)pa.x, (double)pa.x, p2a);
        p2a = fma((double)pa.y, (double)pa.y, p2a);
        p2a = fma((double)pa.z, (double)pa.z, p2a);
        p2a = fma((double)pa.w, (double)pa.w, p2a);
        p2b = fma((double)pb.x, (double)pb.x, p2b);
        p2b = fma((double)pb.y, (double)pb.y, p2b);
        p2b = fma((double)pb.z, (double)pb.z, p2b);
        p2b = fma((double)pb.w, (double)pb.w, p2b);
        Ps[4 * fq + 0][frow] = pa.x;
        Ps[4 * fq + 1][frow] = pa.y;
        Ps[4 * fq + 2][frow] = pa.z;
        Ps[4 * fq + 3][frow] = pa.w;
        Ps[4 * fq + 0][frow + 16] = pb.x;
        Ps[4 * fq + 1][frow + 16] = pb.y;
        Ps[4 * fq + 2][frow + 16] = pb.z;
        Ps[4 * fq + 3][frow + 16] = pb.w;
        __syncthreads();
        #pragma unroll
        for (int k = 0; k < 64; k += 4) {
            float4 xa = *(const float4*)(&Xs[2 * rg][k]);
            float4 xb = *(const float4*)(&Xs[2 * rg + 1][k]);
            double q0 = (double)Ps[k][c],     q1 = (double)Ps[k + 1][c];
            double q2 = (double)Ps[k + 2][c], q3 = (double)Ps[k + 3][c];
            acc0 = fma((double)xa.x, q0, acc0);
            acc0 = fma((double)xa.y, q1, acc0);
            acc0 = fma((double)xa.z, q2, acc0);
            acc0 = fma((double)xa.w, q3, acc0);
            acc1 = fma((double)xb.x, q0, acc1);
            acc1 = fma((double)xb.y, q1, acc1);
            acc1 = fma((double)xb.z, q2, acc1);
            acc1 = fma((double)xb.w, q3, acc1);
        }
        __syncthreads();
    }

    #pragma unroll
    for (int m = 1; m < 16; m <<= 1) {
        xsq += __shfl_xor(xsq, m);
        p2a += __shfl_xor(p2a, m);
        p2b += __shfl_xor(p2b, m);
    }
    if (fq == 0) { x2s[frow] = xsq; p2s[frow] = p2a; p2s[frow + 16] = p2b; }
    __syncthreads();

    const double tmp = (double)fmaxf(fabsf(temp[0]), 0.1f);
    const double myp2 = p2s[c];

    #pragma unroll
    for (int which = 0; which < 2; ++which) {
        double key = myp2 - 2.0 * (which ? acc1 : acc0);
        double k1 = key, k2 = 1.0e300, k3 = 1.1e300;
        int    i1 = c,   i2 = 64,      i3 = 65;
        #pragma unroll
        for (int m = 1; m < 32; m <<= 1) {
            double b1 = __shfl_xor(k1, m), b2 = __shfl_xor(k2, m), b3 = __shfl_xor(k3, m);
            int    j1 = __shfl_xor(i1, m), j2 = __shfl_xor(i2, m), j3 = __shfl_xor(i3, m);
            bool c1 = k1 <= b1;
            double m1 = c1 ? k1 : b1, M1 = c1 ? b1 : k1;
            int   mi1 = c1 ? i1 : j1, Mi1 = c1 ? j1 : i1;
            bool c2 = k2 <= b2;
            double m2 = c2 ? k2 : b2;
            int   mi2 = c2 ? i2 : j2;
            bool c3 = k3 <= b3;
            double m3 = c3 ? k3 : b3;
            int   mi3 = c3 ? i3 : j3;
            bool c4 = M1 <= m2;
            double t2 = c4 ? M1 : m2,  T2 = c4 ? m2 : M1;
            int   ti2 = c4 ? Mi1 : mi2, Ti2 = c4 ? mi2 : Mi1;
            bool c5 = T2 <= m3;
            k1 = m1; i1 = mi1;
            k2 = t2; i2 = ti2;
            k3 = c5 ? T2 : m3; i3 = c5 ? Ti2 : mi3;
        }
        if (c == 0) {
            const int row = rowbase + 2 * rg + which;
            bool tie = (k3 - k2) < TIE_EPS;
            bool take3 = tie && (i3 < i2);
            double ksel = take3 ? k3 : k2;
            int    isel = take3 ? i3 : i2;
            double x2 = x2s[2 * rg + which];
            double d0 = sqrt(fmax(x2 + k1, 0.0));
            double d1 = sqrt(fmax(x2 + ksel, 0.0));
            float e  = expf((float)((d0 - d1) / tmp));
            float w0 = 1.f / (1.f + e);
            route[row] = make_float4(__int_as_float(i1), __int_as_float(isel),
                                     w0, e * w0);
            atomicAdd(&lcnt[i1], 1);
            atomicAdd(&lcnt[32 + isel], 1);
        }
    }
    __syncthreads();
    if (tid < 64) atomicAdd(&counts[tid], lcnt[tid]);
}

// counts[64] -> exclusive prefix per 32-slot segment; segs = (start,end).
__global__ __launch_bounds__(64) void scan_kernel(int* __restrict__ counts,
                                                  int2* __restrict__ segs)
{
    const int tid = threadIdx.x;
    int v = counts[tid];
    int sum = v;
    #pragma unroll
    for (int off = 1; off < 32; off <<= 1) {
        int u = __shfl_up(sum, off, 32);
        if ((tid & 31) >= off) sum += u;
    }
    int excl = sum - v;
    counts[tid] = excl;
    segs[tid] = make_int2(excl, excl + v);
}

__global__ __launch_bounds__(256) void scatter_kernel(
    const float4* __restrict__ route, int* __restrict__ counts,
    int* __restrict__ rowlist0, int* __restrict__ rowlist1)
{
    __shared__ int lcnt[64];
    __shared__ int gbase[64];
    const int tid = threadIdx.x;
    const int i = blockIdx.x * 256 + tid;
    if (tid < 64) lcnt[tid] = 0;
    __syncthreads();
    float4 rt = route[i];
    int p0 = __float_as_int(rt.x);
    int p1 = __float_as_int(rt.y);
    int lp0 = atomicAdd(&lcnt[p0], 1);
    int lp1 = atomicAdd(&lcnt[32 + p1], 1);
    __syncthreads();
    if (tid < 64) gbase[tid] = atomicAdd(&counts[tid], lcnt[tid]);
    __syncthreads();
    rowlist0[gbase[p0] + lp0] = i;
    rowlist1[gbase[32 + p1] + lp1] = i;
}

// ---------------------------------------------------------------------------
// Transpose kernel: Bt[p][k][r] = B[p][r][k], At[p][r][o] = A[p][o][r].
// ---------------------------------------------------------------------------
__global__ __launch_bounds__(256) void transpose_kernel(
    const float* __restrict__ A, const float* __restrict__ B,
    float* __restrict__ At, float* __restrict__ Bt)
{
    __shared__ float T[16 * 68];
    __shared__ float U[64 * 20];
    const int tid = threadIdx.x;
    const int p = blockIdx.x;
    const float4* B4 = (const float4*)(B + (size_t)p * RNK * KDIM);
    const float4* A4 = (const float4*)(A + (size_t)p * OUTD * RNK);
    float4* Bt4 = (float4*)(Bt + (size_t)p * KDIM * RNK);
    float4* At4 = (float4*)(At + (size_t)p * RNK * OUTD);

    for (int c = 0; c < 16; ++c) {
        {
            int r = tid >> 4, kk = tid & 15;
            float4 v = B4[r * 256 + c * 16 + kk];
            *(float4*)&T[r * 68 + kk * 4] = v;
        }
        {
            int o = tid >> 2, rq = tid & 3;
            float4 v = A4[(c * 64 + o) * 4 + rq];
            *(float4*)&U[o * 20 + rq * 4] = v;
        }
        __syncthreads();
        {
            int k = tid >> 2, rq = tid & 3;
            float4 g = make_float4(T[(rq * 4 + 0) * 68 + k], T[(rq * 4 + 1) * 68 + k],
                                   T[(rq * 4 + 2) * 68 + k], T[(rq * 4 + 3) * 68 + k]);
            Bt4[(c * 64 + k) * 4 + rq] = g;
        }
        {
            int r = tid >> 4, ow = tid & 15;
            float4 g = make_float4(U[(ow * 4 + 0) * 20 + r], U[(ow * 4 + 1) * 20 + r],
                                   U[(ow * 4 + 2) * 20 + r], U[(ow * 4 + 3) * 20 + r]);
            At4[r * 256 + c * 16 + ow] = g;
        }
        __syncthreads();
    }
}

// ---------------------------------------------------------------------------
// h v3: block = 256 threads = 4 waves; block owns 4 entries of one segment
// (proto-uniform), wave w owns K-quarter w of all 4 entries. acc = 4 x
// float4 (16 VGPR). 4096 blocks -> 64 waves/CU demanded. Per wave-iter:
// 1 Bt float4 (1KB coalesced) + 4 x scalars (1 line each), 16 iters. XOR
// reduce over kq, LDS quarter-sum, wave 0 stores h[entry][16].
// ---------------------------------------------------------------------------
__global__ __launch_bounds__(256) void h_kernel(
    const float* __restrict__ x, const float* __restrict__ Bt,
    const int* __restrict__ rowlist0, const int* __restrict__ rowlist1,
    const int2* __restrict__ segs, float* __restrict__ hws)
{
    __shared__ float part[4][4][17];   // [quarter][entry][rank+pad]
    __shared__ int xoffs[4];

    const int tid = threadIdx.x;
    const int w = tid >> 6, l = tid & 63;
    const int kq = l >> 2, rq = l & 3;
    const int s = blockIdx.y;             // 0..63 combined segment
    const int slot = s >> 5;
    const int2 sg = segs[s];
    const int* rl = slot ? rowlist1 : rowlist0;
    const float4* Btp = (const float4*)(Bt + (size_t)(s & 31) * KDIM * RNK);
    const int qbase = w * 256;

    for (int c = blockIdx.x; ; c += gridDim.x) {
        const int base = sg.x + c * 4;
        if (base >= sg.y) break;
        const int m = min(4, sg.y - base);

        if (tid < 4) xoffs[tid] = rl[base + min(tid, m - 1)] * KDIM;
        __syncthreads();
        const int x0 = xoffs[0], x1 = xoffs[1], x2 = xoffs[2], x3 = xoffs[3];

        float4 a0 = {0,0,0,0}, a1 = {0,0,0,0}, a2 = {0,0,0,0}, a3 = {0,0,0,0};
        #pragma unroll
        for (int i = 0; i < 16; ++i) {
            const int k = qbase + i * 16 + kq;
            float4 bv = Btp[k * 4 + rq];
            float v0 = x[x0 + k], v1 = x[x1 + k], v2 = x[x2 + k], v3 = x[x3 + k];
            a0.x = fmaf(v0, bv.x, a0.x); a0.y = fmaf(v0, bv.y, a0.y);
            a0.z = fmaf(v0, bv.z, a0.z); a0.w = fmaf(v0, bv.w, a0.w);
            a1.x = fmaf(v1, bv.x, a1.x); a1.y = fmaf(v1, bv.y, a1.y);
            a1.z = fmaf(v1, bv.z, a1.z); a1.w = fmaf(v1, bv.w, a1.w);
            a2.x = fmaf(v2, bv.x, a2.x); a2.y = fmaf(v2, bv.y, a2.y);
            a2.z = fmaf(v2, bv.z, a2.z); a2.w = fmaf(v2, bv.w, a2.w);
            a3.x = fmaf(v3, bv.x, a3.x); a3.y = fmaf(v3, bv.y, a3.y);
            a3.z = fmaf(v3, bv.z, a3.z); a3.w = fmaf(v3, bv.w, a3.w);
        }
        // reduce over kq (lane bits 2..5)
        #pragma unroll
        for (int msk = 4; msk < 64; msk <<= 1) {
            a0.x += __shfl_xor(a0.x, msk); a0.y += __shfl_xor(a0.y, msk);
            a0.z += __shfl_xor(a0.z, msk); a0.w += __shfl_xor(a0.w, msk);
            a1.x += __shfl_xor(a1.x, msk); a1.y += __shfl_xor(a1.y, msk);
            a1.z += __shfl_xor(a1.z, msk); a1.w += __shfl_xor(a1.w, msk);
            a2.x += __shfl_xor(a2.x, msk); a2.y += __shfl_xor(a2.y, msk);
            a2.z += __shfl_xor(a2.z, msk); a2.w += __shfl_xor(a2.w, msk);
            a3.x += __shfl_xor(a3.x, msk); a3.y += __shfl_xor(a3.y, msk);
            a3.z += __shfl_xor(a3.z, msk); a3.w += __shfl_xor(a3.w, msk);
        }
        if (kq == 0) {
            *(float4*)&part[w][0][rq * 4] = a0;
            *(float4*)&part[w][1][rq * 4] = a1;
            *(float4*)&part[w][2][rq * 4] = a2;
            *(float4*)&part[w][3][rq * 4] = a3;
        }
        __syncthreads();
        if (tid < 64) {
            const int e = tid >> 4, r = tid & 15;
            if (e < m) {
                float hsum = part[0][e][r] + part[1][e][r]
                           + part[2][e][r] + part[3][e][r];
                hws[(size_t)(slot * ROWS_TOTAL + base + e) * 16 + r] = hsum;
            }
        }
        __syncthreads();
    }
}

// ---------------------------------------------------------------------------
// y v2: one wave per 4 sorted same-proto entries; grid-stride chunks within
// segment. Per j-step acc = 4 x float4 (16 VGPR live). Per At float4 load
// -> 16 FMA. out writes 1KB-contiguous per entry; slot0 stores, slot1 RMW.
// ---------------------------------------------------------------------------
__global__ __launch_bounds__(64) void y_kernel(
    const float* __restrict__ At, const float* __restrict__ bias,
    const float4* __restrict__ route, const int* __restrict__ rowlist,
    const int2* __restrict__ segs, const float* __restrict__ hws,
    float* __restrict__ out, int slot)
{
    __shared__ float hsm[4][16];
    __shared__ int rows[4];
    __shared__ float wts[4];

    const int l = threadIdx.x;
    const int p = blockIdx.y;
    const int2 sg = segs[slot * 32 + p];
    const float4* Atp = (const float4*)(At + (size_t)p * RNK * OUTD);
    const float4* bp  = (const float4*)(bias + (size_t)p * OUTD);

    for (int c = blockIdx.x; ; c += gridDim.x) {
        const int base = sg.x + c * 4;
        if (base >= sg.y) break;
        const int m = min(4, sg.y - base);
        const int gbase = slot * ROWS_TOTAL + base;

        if (l < 4) {
            int rr = rowlist[base + min(l, m - 1)];
            rows[l] = rr;
            float4 rt = route[rr];
            wts[l] = slot ? rt.w : rt.z;
        }
        {
            const int e = l >> 4, r = l & 15;
            hsm[e][r] = hws[(size_t)(gbase + min(e, m - 1)) * 16 + r];
        }
        __syncthreads();

        #pragma unroll
        for (int j = 0; j < 4; ++j) {
            const int f4 = j * 64 + l;
            float4 bb = bp[f4];
            float4 c0 = bb, c1 = bb, c2 = bb, c3 = bb;
            #pragma unroll
            for (int r = 0; r < 16; ++r) {
                float4 a = Atp[r * 256 + f4];
                float h0 = hsm[0][r], h1 = hsm[1][r], h2 = hsm[2][r], h3 = hsm[3][r];
                c0.x = fmaf(h0, a.x, c0.x); c0.y = fmaf(h0, a.y, c0.y);
                c0.z = fmaf(h0, a.z, c0.z); c0.w = fmaf(h0, a.w, c0.w);
                c1.x = fmaf(h1, a.x, c1.x); c1.y = fmaf(h1, a.y, c1.y);
                c1.z = fmaf(h1, a.z, c1.z); c1.w = fmaf(h1, a.w, c1.w);
                c2.x = fmaf(h2, a.x, c2.x); c2.y = fmaf(h2, a.y, c2.y);
                c2.z = fmaf(h2, a.z, c2.z); c2.w = fmaf(h2, a.w, c2.w);
                c3.x = fmaf(h3, a.x, c3.x); c3.y = fmaf(h3, a.y, c3.y);
                c3.z = fmaf(h3, a.z, c3.z); c3.w = fmaf(h3, a.w, c3.w);
            }
            #pragma unroll
            for (int e = 0; e < 4; ++e) {
                if (e < m) {
                    float4 cc = (e == 0) ? c0 : (e == 1) ? c1 : (e == 2) ? c2 : c3;
                    const float w = wts[e];
                    float4 v = make_float4(w * cc.x, w * cc.y, w * cc.z, w * cc.w);
                    float4* dst = (float4*)(out + (size_t)rows[e] * OUTD + f4 * 4);
                    if (slot) {
                        float4 old = *dst;
                        v.x += old.x; v.y += old.y; v.z += old.z; v.w += old.w;
                    }
                    *dst = v;
                }
            }
        }
        __syncthreads();
    }
}

extern "C" void kernel_launch(void* const* d_in, const int* in_sizes, int n_in,
                              void* d_out, int out_size, void* d_ws, size_t ws_size,
                              hipStream_t stream) {
    const float* x     = (const float*)d_in[0];
    const float* proto = (const float*)d_in[1];
    const float* B     = (const float*)d_in[2];
    const float* A     = (const float*)d_in[3];
    const float* bias  = (const float*)d_in[4];
    const float* temp  = (const float*)d_in[5];
    float* out = (float*)d_out;

    char* wsb = (char*)d_ws;
    float4* route = (float4*)wsb;                              // 128 KB
    int* rowlist0 = (int*)(wsb + 131072);                      // 32 KB
    int* rowlist1 = rowlist0 + ROWS_TOTAL;                     // 32 KB
    int* counts   = rowlist1 + ROWS_TOTAL;                     // 256 B
    int2* segs    = (int2*)(counts + 64);                      // 512 B
    float* Bt     = (float*)(wsb + 262144);                    // 2 MB
    float* At     = (float*)(wsb + 262144 + 2097152);          // 2 MB
    float* hws    = (float*)(wsb + 262144 + 2 * 2097152);      // 1 MB

    hipMemsetAsync(counts, 0, 64 * sizeof(int), stream);
    transpose_kernel<<<NPROTO, 256, 0, stream>>>(A, B, At, Bt);
    route_kernel<<<ROWS_TOTAL / 16, 256, 0, stream>>>(x, proto, temp, route, counts);
    scan_kernel<<<1, 64, 0, stream>>>(counts, segs);
    scatter_kernel<<<ROWS_TOTAL / 256, 256, 0, stream>>>(route, counts, rowlist0, rowlist1);
    h_kernel<<<dim3(64, 64), 256, 0, stream>>>(x, Bt, rowlist0, rowlist1, segs, hws);
    y_kernel<<<dim3(64, NPROTO), 64, 0, stream>>>(At, bias, route, rowlist0, segs, hws, out, 0);
    y_kernel<<<dim3(64, NPROTO), 64, 0, stream>>>(At, bias, route, rowlist1, segs, hws, out, 1);
}